// Round 1
// baseline (1891.481 us; speedup 1.0000x reference)
//
#include <hip/hip_runtime.h>
#include <stdint.h>

#define NN 2048
#define TT 10
#define KST 5

typedef float f32x4 __attribute__((ext_vector_type(4)));
typedef __bf16 bf16x8 __attribute__((ext_vector_type(8)));

using as3_void = __attribute__((address_space(3))) void;
using as1_const_void = const __attribute__((address_space(1))) void;

__device__ __forceinline__ unsigned short f2bf_bits(float f) {
    unsigned u = __builtin_bit_cast(unsigned, f);
    unsigned r = u + 0x7FFFu + ((u >> 16) & 1u);   // RNE
    return (unsigned short)(r >> 16);
}

// ---------------- deg[t][i] = sum_j x[i][t][j] + 1e-8 ----------------
__global__ __launch_bounds__(256) void deg_kernel(const float* __restrict__ x,
                                                  float* __restrict__ deg) {
    const int i = blockIdx.x;   // node (first axis of x)
    const int t = blockIdx.y;
    const int tid = threadIdx.x;
    const float4* r4 = (const float4*)(x + ((size_t)i * TT + t) * NN);
    float4 a = r4[tid];
    float4 b = r4[tid + 256];
    float s = a.x + a.y + a.z + a.w + b.x + b.y + b.z + b.w;
    #pragma unroll
    for (int m = 32; m >= 1; m >>= 1) s += __shfl_xor(s, m, 64);
    __shared__ float red[4];
    if ((tid & 63) == 0) red[tid >> 6] = s;
    __syncthreads();
    if (tid == 0) deg[(size_t)t * NN + i] = red[0] + red[1] + red[2] + red[3] + 1e-8f;
}

// ------------- GnT[tl][n][k] = bf16( x[k][t][n] / deg[t][k] ) -------------
__global__ __launch_bounds__(256) void gnt_kernel(const float* __restrict__ x,
                                                  const float* __restrict__ deg,
                                                  unsigned short* __restrict__ gnt,
                                                  int t0) {
    const int tl = blockIdx.z;
    const int t  = t0 + tl;
    const int n0 = blockIdx.x * 64;
    const int k0 = blockIdx.y * 64;
    __shared__ float tile[64][65];
    const int tx = threadIdx.x & 63;
    const int ty = threadIdx.x >> 6;
    #pragma unroll
    for (int p = 0; p < 16; ++p) {
        int kr = p * 4 + ty;
        float rd = 1.0f / deg[(size_t)t * NN + k0 + kr];
        tile[kr][tx] = x[(((size_t)(k0 + kr)) * TT + t) * NN + n0 + tx] * rd;
    }
    __syncthreads();
    unsigned short* dst = gnt + (size_t)tl * NN * NN;
    #pragma unroll
    for (int p = 0; p < 16; ++p) {
        int nr = p * 4 + ty;
        dst[(size_t)(n0 + nr) * NN + k0 + tx] = f2bf_bits(tile[tx][nr]);
    }
}

// ---- P1 = w0*Gn + (1-w0)*I ; S(out) = P1 ; P(bf16) = P1 ----
__global__ __launch_bounds__(256) void init_kernel(const float* __restrict__ x,
                                                   const float* __restrict__ deg,
                                                   const float* __restrict__ w,
                                                   float* __restrict__ out,
                                                   unsigned short* __restrict__ P,
                                                   int t0) {
    const int tl = blockIdx.z;
    const int t  = t0 + tl;
    float w0 = w[t * KST + 0];
    w0 = fminf(fmaxf(w0, 0.0f), 1.0f);
    const float om = 1.0f - w0;
    const int f4 = blockIdx.x * 256 + threadIdx.x;    // 0 .. NN*NN/4-1
    const int m  = f4 >> 9;                            // / (NN/4)
    const int n4 = (f4 & 511) * 4;
    const size_t xoff = ((size_t)m * TT + t) * NN + n4;
    float4 g = *(const float4*)(x + xoff);
    const float rd = 1.0f / deg[(size_t)t * NN + m];
    float v0 = w0 * (g.x * rd) + ((n4 + 0) == m ? om : 0.0f);
    float v1 = w0 * (g.y * rd) + ((n4 + 1) == m ? om : 0.0f);
    float v2 = w0 * (g.z * rd) + ((n4 + 2) == m ? om : 0.0f);
    float v3 = w0 * (g.w * rd) + ((n4 + 3) == m ? om : 0.0f);
    float4 v; v.x = v0; v.y = v1; v.z = v2; v.w = v3;
    *(float4*)(out + xoff) = v;   // S init lands directly in d_out ([N,T,N])
    unsigned short pb[4] = {f2bf_bits(v0), f2bf_bits(v1), f2bf_bits(v2), f2bf_bits(v3)};
    *(uint2*)(P + (size_t)tl * NN * NN + (size_t)m * NN + n4) = *(const uint2*)pb;
}

// ---- one RWR step for all t in chunk: acc = Pprev @ Gn (via GnT),
//      val = wk*acc + (1-wk)*I ; S(out) += val ; Pnext = bf16(val) ----
__global__ __launch_bounds__(256) void gemm_step(const unsigned short* __restrict__ Pprev,
                                                 const unsigned short* __restrict__ gnt,
                                                 const float* __restrict__ w,
                                                 float* __restrict__ out,
                                                 unsigned short* __restrict__ Pnext,
                                                 int t0, int kstep, int write_p) {
    const int tl = blockIdx.z;
    const int t  = t0 + tl;
    const int tn = blockIdx.x;
    const int tm = blockIdx.y;

    __shared__ unsigned short As[128 * 32];   // A tile  [m][k]
    __shared__ unsigned short Bs[128 * 32];   // BT tile [n][k]

    const int tid  = threadIdx.x;
    const int lane = tid & 63;
    const int wv   = tid >> 6;        // 4 waves
    const int wm   = wv >> 1;         // 2x2 wave grid, 64x64 each
    const int wn   = wv & 1;
    const int quad = lane >> 4;
    const int lr   = lane & 15;

    const unsigned short* Ab = Pprev + (size_t)tl * NN * NN;
    const unsigned short* Bb = gnt   + (size_t)tl * NN * NN;

    const int srow = lane >> 2;        // 0..15 row within a 16-row chunk
    const int sko  = (lane & 3) * 8;   // 8 bf16 = 16B per lane

    f32x4 acc[4][4];
    #pragma unroll
    for (int i = 0; i < 4; ++i)
        #pragma unroll
        for (int j = 0; j < 4; ++j)
            acc[i][j] = (f32x4){0.0f, 0.0f, 0.0f, 0.0f};

    for (int kt = 0; kt < NN / 32; ++kt) {
        const int k0 = kt * 32;
        #pragma unroll
        for (int ii = 0; ii < 2; ++ii) {
            const int chunk = ii * 4 + wv;            // 8 x 1KB chunks per tile
            const int row   = chunk * 16 + srow;
            const unsigned short* ga = Ab + (size_t)(tm * 128 + row) * NN + k0 + sko;
            __builtin_amdgcn_global_load_lds((as1_const_void*)ga,
                                             (as3_void*)(As + chunk * 512), 16, 0, 0);
            const unsigned short* gb = Bb + (size_t)(tn * 128 + row) * NN + k0 + sko;
            __builtin_amdgcn_global_load_lds((as1_const_void*)gb,
                                             (as3_void*)(Bs + chunk * 512), 16, 0, 0);
        }
        __syncthreads();

        bf16x8 af[4], bf[4];
        #pragma unroll
        for (int i = 0; i < 4; ++i)
            af[i] = *(const bf16x8*)(As + (wm * 64 + i * 16 + lr) * 32 + quad * 8);
        #pragma unroll
        for (int j = 0; j < 4; ++j)
            bf[j] = *(const bf16x8*)(Bs + (wn * 64 + j * 16 + lr) * 32 + quad * 8);
        #pragma unroll
        for (int i = 0; i < 4; ++i)
            #pragma unroll
            for (int j = 0; j < 4; ++j)
                acc[i][j] = __builtin_amdgcn_mfma_f32_16x16x32_bf16(af[i], bf[j], acc[i][j], 0, 0, 0);
        __syncthreads();
    }

    float wk = w[t * KST + kstep];
    wk = fminf(fmaxf(wk, 0.0f), 1.0f);
    const float om = 1.0f - wk;

    #pragma unroll
    for (int i = 0; i < 4; ++i) {
        #pragma unroll
        for (int v = 0; v < 4; ++v) {
            const int m = tm * 128 + wm * 64 + i * 16 + quad * 4 + v;
            const size_t ob = ((size_t)m * TT + t) * NN;
            const size_t pbase = (size_t)tl * NN * NN + (size_t)m * NN;
            #pragma unroll
            for (int j = 0; j < 4; ++j) {
                const int n = tn * 128 + wn * 64 + j * 16 + lr;
                float val = wk * acc[i][j][v] + (m == n ? om : 0.0f);
                out[ob + n] += val;
                if (write_p) Pnext[pbase + n] = f2bf_bits(val);
            }
        }
    }
}

// ---------------- in-place LayerNorm over each row of out ----------------
__global__ __launch_bounds__(256) void ln_kernel(const float* __restrict__ gamma,
                                                 const float* __restrict__ beta,
                                                 float* __restrict__ out) {
    const size_t base = (size_t)blockIdx.x * NN;
    const int tid = threadIdx.x;
    const int j = tid * 8;
    float4 a = *(const float4*)(out + base + j);
    float4 c = *(const float4*)(out + base + j + 4);

    float s = a.x + a.y + a.z + a.w + c.x + c.y + c.z + c.w;
    #pragma unroll
    for (int m = 32; m >= 1; m >>= 1) s += __shfl_xor(s, m, 64);
    __shared__ float red[4];
    if ((tid & 63) == 0) red[tid >> 6] = s;
    __syncthreads();
    const float mu = (red[0] + red[1] + red[2] + red[3]) * (1.0f / NN);

    float dx0 = a.x - mu, dx1 = a.y - mu, dx2 = a.z - mu, dx3 = a.w - mu;
    float dx4 = c.x - mu, dx5 = c.y - mu, dx6 = c.z - mu, dx7 = c.w - mu;
    float q = dx0*dx0 + dx1*dx1 + dx2*dx2 + dx3*dx3 + dx4*dx4 + dx5*dx5 + dx6*dx6 + dx7*dx7;
    __syncthreads();
    #pragma unroll
    for (int m = 32; m >= 1; m >>= 1) q += __shfl_xor(q, m, 64);
    if ((tid & 63) == 0) red[tid >> 6] = q;
    __syncthreads();
    const float var = (red[0] + red[1] + red[2] + red[3]) * (1.0f / NN);
    const float sc = rsqrtf(var + 1e-5f);

    float4 g0 = *(const float4*)(gamma + j);
    float4 g1 = *(const float4*)(gamma + j + 4);
    float4 b0 = *(const float4*)(beta + j);
    float4 b1 = *(const float4*)(beta + j + 4);
    float4 o0, o1;
    o0.x = dx0 * sc * g0.x + b0.x;  o0.y = dx1 * sc * g0.y + b0.y;
    o0.z = dx2 * sc * g0.z + b0.z;  o0.w = dx3 * sc * g0.w + b0.w;
    o1.x = dx4 * sc * g1.x + b1.x;  o1.y = dx5 * sc * g1.y + b1.y;
    o1.z = dx6 * sc * g1.z + b1.z;  o1.w = dx7 * sc * g1.w + b1.w;
    *(float4*)(out + base + j)     = o0;
    *(float4*)(out + base + j + 4) = o1;
}

extern "C" void kernel_launch(void* const* d_in, const int* in_sizes, int n_in,
                              void* d_out, int out_size, void* d_ws, size_t ws_size,
                              hipStream_t stream) {
    (void)in_sizes; (void)n_in; (void)out_size;
    const float* x     = (const float*)d_in[0];
    const float* w     = (const float*)d_in[1];
    const float* gamma = (const float*)d_in[2];
    const float* beta  = (const float*)d_in[3];
    float* out = (float*)d_out;

    char* ws = (char*)d_ws;
    float* deg = (float*)ws;
    size_t off = ((size_t)TT * NN * sizeof(float) + 255) & ~(size_t)255;
    const size_t per_t = (size_t)NN * NN * sizeof(unsigned short);   // 8.4 MB
    size_t avail = ws_size > off ? ws_size - off : 0;
    int TB = (int)(avail / (3 * per_t));
    if (TB < 1) TB = 1;
    if (TB > TT) TB = TT;
    unsigned short* gnt = (unsigned short*)(ws + off);
    unsigned short* Pa  = (unsigned short*)(ws + off + (size_t)TB * per_t);
    unsigned short* Pb  = (unsigned short*)(ws + off + 2 * (size_t)TB * per_t);

    deg_kernel<<<dim3(NN, TT), 256, 0, stream>>>(x, deg);

    for (int t0 = 0; t0 < TT; t0 += TB) {
        const int tb = (TT - t0) < TB ? (TT - t0) : TB;
        gnt_kernel<<<dim3(32, 32, tb), 256, 0, stream>>>(x, deg, gnt, t0);
        init_kernel<<<dim3(4096, 1, tb), 256, 0, stream>>>(x, deg, w, out, Pa, t0);
        for (int k = 1; k < KST; ++k) {
            unsigned short* Pp = (k & 1) ? Pa : Pb;
            unsigned short* Pn = (k & 1) ? Pb : Pa;
            gemm_step<<<dim3(16, 16, tb), 256, 0, stream>>>(Pp, gnt, w, out, Pn,
                                                            t0, k, (k < KST - 1) ? 1 : 0);
        }
    }

    ln_kernel<<<dim3(NN * TT), 256, 0, stream>>>(gamma, beta, out);
}

// Round 2
// 1420.938 us; speedup vs baseline: 1.3311x; 1.3311x over previous
//
#include <hip/hip_runtime.h>
#include <stdint.h>

#define NN 2048
#define TT 10
#define KST 5

typedef float f32x4 __attribute__((ext_vector_type(4)));
typedef __bf16 bf16x8 __attribute__((ext_vector_type(8)));
typedef unsigned short u16x8 __attribute__((ext_vector_type(8)));

using as3_void = __attribute__((address_space(3))) void;
using as1_const_void = const __attribute__((address_space(1))) void;

__device__ __forceinline__ unsigned short f2bf_bits(float f) {
    unsigned u = __builtin_bit_cast(unsigned, f);
    unsigned r = u + 0x7FFFu + ((u >> 16) & 1u);   // RNE
    return (unsigned short)(r >> 16);
}
__device__ __forceinline__ float bf2f(unsigned short b) {
    return __builtin_bit_cast(float, ((unsigned)b) << 16);
}

// ---------------- deg[t][i] = sum_j x[i][t][j] + 1e-8 ----------------
__global__ __launch_bounds__(256) void deg_kernel(const float* __restrict__ x,
                                                  float* __restrict__ deg) {
    const int i = blockIdx.x;
    const int t = blockIdx.y;
    const int tid = threadIdx.x;
    const float4* r4 = (const float4*)(x + ((size_t)i * TT + t) * NN);
    float4 a = r4[tid];
    float4 b = r4[tid + 256];
    float s = a.x + a.y + a.z + a.w + b.x + b.y + b.z + b.w;
    #pragma unroll
    for (int m = 32; m >= 1; m >>= 1) s += __shfl_xor(s, m, 64);
    __shared__ float red[4];
    if ((tid & 63) == 0) red[tid >> 6] = s;
    __syncthreads();
    if (tid == 0) deg[(size_t)t * NN + i] = red[0] + red[1] + red[2] + red[3] + 1e-8f;
}

// ---- GnT[tl][n][k] = bf16(Gn[k][n]) AND P1[tl][k][n] = bf16(w0*Gn + (1-w0)I) ----
__global__ __launch_bounds__(256) void gnt_init_kernel(const float* __restrict__ x,
                                                       const float* __restrict__ deg,
                                                       const float* __restrict__ w,
                                                       unsigned short* __restrict__ gnt,
                                                       unsigned short* __restrict__ p1,
                                                       int t0) {
    const int tl = blockIdx.z;
    const int t  = t0 + tl;
    float w0 = w[t * KST + 0];
    w0 = fminf(fmaxf(w0, 0.0f), 1.0f);
    const float om = 1.0f - w0;
    const int n0 = blockIdx.x * 64;
    const int k0 = blockIdx.y * 64;
    __shared__ float tile[64][65];
    const int tx = threadIdx.x & 63;
    const int ty = threadIdx.x >> 6;
    unsigned short* p1dst = p1 + (size_t)tl * NN * NN;
    #pragma unroll
    for (int p = 0; p < 16; ++p) {
        int kr = p * 4 + ty;
        float rd = 1.0f / deg[(size_t)t * NN + k0 + kr];
        float v = x[(((size_t)(k0 + kr)) * TT + t) * NN + n0 + tx] * rd;
        tile[kr][tx] = v;
        float pv = w0 * v + ((k0 + kr) == (n0 + tx) ? om : 0.0f);
        p1dst[(size_t)(k0 + kr) * NN + n0 + tx] = f2bf_bits(pv);
    }
    __syncthreads();
    unsigned short* dst = gnt + (size_t)tl * NN * NN;
    #pragma unroll
    for (int p = 0; p < 16; ++p) {
        int nr = p * 4 + ty;
        dst[(size_t)(n0 + nr) * NN + k0 + tx] = f2bf_bits(tile[tx][nr]);
    }
}

// ---- P_next = wk*(Pprev @ Gn) + (1-wk)*I, bf16, double-buffered LDS ----
__global__ __launch_bounds__(256) void gemm_step(const unsigned short* __restrict__ Pprev,
                                                 const unsigned short* __restrict__ gnt,
                                                 const float* __restrict__ w,
                                                 unsigned short* __restrict__ Pnext,
                                                 int t0, int kstep) {
    const int tl = blockIdx.z;
    const int t  = t0 + tl;
    const int tn = blockIdx.x;
    const int tm = blockIdx.y;

    __shared__ unsigned short As[2][128 * 32];
    __shared__ unsigned short Bs[2][128 * 32];

    const int tid  = threadIdx.x;
    const int lane = tid & 63;
    const int wv   = tid >> 6;
    const int wm   = wv >> 1;
    const int wn   = wv & 1;
    const int quad = lane >> 4;
    const int lr   = lane & 15;

    const unsigned short* Ab = Pprev + (size_t)tl * NN * NN;
    const unsigned short* Bb = gnt   + (size_t)tl * NN * NN;

    const int srow = lane >> 2;
    const int sko  = (lane & 3) * 8;

    f32x4 acc[4][4];
    #pragma unroll
    for (int i = 0; i < 4; ++i)
        #pragma unroll
        for (int j = 0; j < 4; ++j)
            acc[i][j] = (f32x4){0.0f, 0.0f, 0.0f, 0.0f};

    // stage K-tile kt into buffer b
    auto stage = [&](int kt, int b) {
        const int k0 = kt * 32;
        #pragma unroll
        for (int ii = 0; ii < 2; ++ii) {
            const int chunk = ii * 4 + wv;
            const int row   = chunk * 16 + srow;
            const unsigned short* ga = Ab + (size_t)(tm * 128 + row) * NN + k0 + sko;
            __builtin_amdgcn_global_load_lds((as1_const_void*)ga,
                                             (as3_void*)(&As[b][chunk * 512]), 16, 0, 0);
            const unsigned short* gb = Bb + (size_t)(tn * 128 + row) * NN + k0 + sko;
            __builtin_amdgcn_global_load_lds((as1_const_void*)gb,
                                             (as3_void*)(&Bs[b][chunk * 512]), 16, 0, 0);
        }
    };

    stage(0, 0);

    for (int kt = 0; kt < NN / 32; ++kt) {
        const int b = kt & 1;
        __syncthreads();           // drains this wave's vmcnt (incl. prefetch), syncs block
        if (kt + 1 < NN / 32) stage(kt + 1, b ^ 1);   // prefetch overlaps compute below

        bf16x8 af[4], bfr[4];
        #pragma unroll
        for (int i = 0; i < 4; ++i)
            af[i] = *(const bf16x8*)(&As[b][(wm * 64 + i * 16 + lr) * 32 + quad * 8]);
        #pragma unroll
        for (int j = 0; j < 4; ++j)
            bfr[j] = *(const bf16x8*)(&Bs[b][(wn * 64 + j * 16 + lr) * 32 + quad * 8]);
        #pragma unroll
        for (int i = 0; i < 4; ++i)
            #pragma unroll
            for (int j = 0; j < 4; ++j)
                acc[i][j] = __builtin_amdgcn_mfma_f32_16x16x32_bf16(af[i], bfr[j], acc[i][j], 0, 0, 0);
    }

    float wk = w[t * KST + kstep];
    wk = fminf(fmaxf(wk, 0.0f), 1.0f);
    const float om = 1.0f - wk;

    #pragma unroll
    for (int i = 0; i < 4; ++i) {
        #pragma unroll
        for (int v = 0; v < 4; ++v) {
            const int m = tm * 128 + wm * 64 + i * 16 + quad * 4 + v;
            const size_t pbase = (size_t)tl * NN * NN + (size_t)m * NN;
            #pragma unroll
            for (int j = 0; j < 4; ++j) {
                const int n = tn * 128 + wn * 64 + j * 16 + lr;
                float val = wk * acc[i][j][v] + (m == n ? om : 0.0f);
                Pnext[pbase + n] = f2bf_bits(val);
            }
        }
    }
}

// ---- out[m][t][:] = LayerNorm( sum_k P_k[m][:] ), P_k bf16 ----
__global__ __launch_bounds__(256) void ln_kernel(const unsigned short* __restrict__ Pall,
                                                 const float* __restrict__ gamma,
                                                 const float* __restrict__ beta,
                                                 float* __restrict__ out,
                                                 int t0, size_t strideK) {
    const int m  = blockIdx.x;
    const int tl = blockIdx.y;
    const int t  = t0 + tl;
    const int tid = threadIdx.x;
    const int j = tid * 8;

    const size_t rbase = (size_t)tl * NN * NN + (size_t)m * NN + j;
    float v[8] = {0, 0, 0, 0, 0, 0, 0, 0};
    #pragma unroll
    for (int k = 0; k < KST; ++k) {
        u16x8 pv = *(const u16x8*)(Pall + (size_t)k * strideK + rbase);
        #pragma unroll
        for (int e = 0; e < 8; ++e) v[e] += bf2f(pv[e]);
    }

    float s = 0.0f;
    #pragma unroll
    for (int e = 0; e < 8; ++e) s += v[e];
    #pragma unroll
    for (int mm = 32; mm >= 1; mm >>= 1) s += __shfl_xor(s, mm, 64);
    __shared__ float red[4];
    if ((tid & 63) == 0) red[tid >> 6] = s;
    __syncthreads();
    const float mu = (red[0] + red[1] + red[2] + red[3]) * (1.0f / NN);

    float q = 0.0f;
    float dx[8];
    #pragma unroll
    for (int e = 0; e < 8; ++e) { dx[e] = v[e] - mu; q += dx[e] * dx[e]; }
    __syncthreads();
    #pragma unroll
    for (int mm = 32; mm >= 1; mm >>= 1) q += __shfl_xor(q, mm, 64);
    if ((tid & 63) == 0) red[tid >> 6] = q;
    __syncthreads();
    const float var = (red[0] + red[1] + red[2] + red[3]) * (1.0f / NN);
    const float sc = rsqrtf(var + 1e-5f);

    float4 g0 = *(const float4*)(gamma + j);
    float4 g1 = *(const float4*)(gamma + j + 4);
    float4 b0 = *(const float4*)(beta + j);
    float4 b1 = *(const float4*)(beta + j + 4);
    const size_t ob = ((size_t)m * TT + t) * NN + j;
    float4 o0, o1;
    o0.x = dx[0] * sc * g0.x + b0.x;  o0.y = dx[1] * sc * g0.y + b0.y;
    o0.z = dx[2] * sc * g0.z + b0.z;  o0.w = dx[3] * sc * g0.w + b0.w;
    o1.x = dx[4] * sc * g1.x + b1.x;  o1.y = dx[5] * sc * g1.y + b1.y;
    o1.z = dx[6] * sc * g1.z + b1.z;  o1.w = dx[7] * sc * g1.w + b1.w;
    *(float4*)(out + ob)     = o0;
    *(float4*)(out + ob + 4) = o1;
}

extern "C" void kernel_launch(void* const* d_in, const int* in_sizes, int n_in,
                              void* d_out, int out_size, void* d_ws, size_t ws_size,
                              hipStream_t stream) {
    (void)in_sizes; (void)n_in; (void)out_size;
    const float* x     = (const float*)d_in[0];
    const float* w     = (const float*)d_in[1];
    const float* gamma = (const float*)d_in[2];
    const float* beta  = (const float*)d_in[3];
    float* out = (float*)d_out;

    char* ws = (char*)d_ws;
    float* deg = (float*)ws;
    size_t off = ((size_t)TT * NN * sizeof(float) + 255) & ~(size_t)255;
    const size_t per_t = (size_t)NN * NN * sizeof(unsigned short);   // 8 MB
    size_t avail = ws_size > off ? ws_size - off : 0;
    // 1 gnt buffer + KST P buffers per t
    int TB = (int)(avail / ((1 + KST) * per_t));
    if (TB < 1) TB = 1;
    if (TB > TT) TB = TT;
    unsigned short* gnt  = (unsigned short*)(ws + off);
    unsigned short* Pall = gnt + (size_t)TB * NN * NN;
    const size_t strideK = (size_t)TB * NN * NN;   // elements per k-buffer

    deg_kernel<<<dim3(NN, TT), 256, 0, stream>>>(x, deg);

    for (int t0 = 0; t0 < TT; t0 += TB) {
        const int tb = (TT - t0) < TB ? (TT - t0) : TB;
        gnt_init_kernel<<<dim3(32, 32, tb), 256, 0, stream>>>(x, deg, w, gnt, Pall, t0);
        for (int k = 2; k <= KST; ++k) {
            const unsigned short* Pp = Pall + (size_t)(k - 2) * strideK;
            unsigned short*       Pn = Pall + (size_t)(k - 1) * strideK;
            gemm_step<<<dim3(16, 16, tb), 256, 0, stream>>>(Pp, gnt, w, Pn, t0, k - 1);
        }
        ln_kernel<<<dim3(NN, tb), 256, 0, stream>>>(Pall, gamma, beta, out, t0, strideK);
    }
}

// Round 3
// 1321.295 us; speedup vs baseline: 1.4315x; 1.0754x over previous
//
#include <hip/hip_runtime.h>
#include <stdint.h>

#define NN 2048
#define TT 10
#define KST 5
#define NKT (NN / 32)

typedef float f32x4 __attribute__((ext_vector_type(4)));
typedef __bf16 bf16x8 __attribute__((ext_vector_type(8)));
typedef unsigned short u16x8 __attribute__((ext_vector_type(8)));

using as3_void = __attribute__((address_space(3))) void;
using as1_const_void = const __attribute__((address_space(1))) void;

__device__ __forceinline__ unsigned short f2bf_bits(float f) {
    unsigned u = __builtin_bit_cast(unsigned, f);
    unsigned r = u + 0x7FFFu + ((u >> 16) & 1u);   // RNE
    return (unsigned short)(r >> 16);
}
__device__ __forceinline__ float bf2f(unsigned short b) {
    return __builtin_bit_cast(float, ((unsigned)b) << 16);
}

// ---------------- deg[t][i] = sum_j x[i][t][j] + 1e-8 ----------------
__global__ __launch_bounds__(256) void deg_kernel(const float* __restrict__ x,
                                                  float* __restrict__ deg) {
    const int i = blockIdx.x;
    const int t = blockIdx.y;
    const int tid = threadIdx.x;
    const float4* r4 = (const float4*)(x + ((size_t)i * TT + t) * NN);
    float4 a = r4[tid];
    float4 b = r4[tid + 256];
    float s = a.x + a.y + a.z + a.w + b.x + b.y + b.z + b.w;
    #pragma unroll
    for (int m = 32; m >= 1; m >>= 1) s += __shfl_xor(s, m, 64);
    __shared__ float red[4];
    if ((tid & 63) == 0) red[tid >> 6] = s;
    __syncthreads();
    if (tid == 0) deg[(size_t)t * NN + i] = red[0] + red[1] + red[2] + red[3] + 1e-8f;
}

// ---- GnT[tl][n][k] = bf16(Gn[k][n]) AND P1[tl][k][n] = bf16(w0*Gn + (1-w0)I) ----
__global__ __launch_bounds__(256) void gnt_init_kernel(const float* __restrict__ x,
                                                       const float* __restrict__ deg,
                                                       const float* __restrict__ w,
                                                       unsigned short* __restrict__ gnt,
                                                       unsigned short* __restrict__ p1,
                                                       int t0) {
    const int tl = blockIdx.z;
    const int t  = t0 + tl;
    float w0 = w[t * KST + 0];
    w0 = fminf(fmaxf(w0, 0.0f), 1.0f);
    const float om = 1.0f - w0;
    const int n0 = blockIdx.x * 64;
    const int k0 = blockIdx.y * 64;
    __shared__ float tile[64][65];
    const int tx = threadIdx.x & 63;
    const int ty = threadIdx.x >> 6;
    unsigned short* p1dst = p1 + (size_t)tl * NN * NN;
    #pragma unroll
    for (int p = 0; p < 16; ++p) {
        int kr = p * 4 + ty;
        float rd = 1.0f / deg[(size_t)t * NN + k0 + kr];
        float v = x[(((size_t)(k0 + kr)) * TT + t) * NN + n0 + tx] * rd;
        tile[kr][tx] = v;
        float pv = w0 * v + ((k0 + kr) == (n0 + tx) ? om : 0.0f);
        p1dst[(size_t)(k0 + kr) * NN + n0 + tx] = f2bf_bits(pv);
    }
    __syncthreads();
    unsigned short* dst = gnt + (size_t)tl * NN * NN;
    #pragma unroll
    for (int p = 0; p < 16; ++p) {
        int nr = p * 4 + ty;
        dst[(size_t)(n0 + nr) * NN + k0 + tx] = f2bf_bits(tile[tx][nr]);
    }
}

// ---- P_next = wk*(Pprev @ Gn) + (1-wk)*I, bf16.
//      Triple-buffered LDS, distance-2 prefetch, raw barrier w/ vmcnt(4). ----
__global__ __launch_bounds__(256) void gemm_step(const unsigned short* __restrict__ Pprev,
                                                 const unsigned short* __restrict__ gnt,
                                                 const float* __restrict__ w,
                                                 unsigned short* __restrict__ Pnext,
                                                 int t0, int kstep) {
    // XCD-aware swizzle: flat -> (tl, tm, tn). Assumes block i lands on XCD i%8.
    // 4x4 super-tiles: A-strips(2MB)+B-strips(2MB) fit one XCD's 4MB L2.
    const int flat   = blockIdx.x;
    const int xcd    = flat & 7;
    const int local  = flat >> 3;
    const int within = local & 15;
    const int st     = xcd + 8 * (local >> 4);
    const int tl     = st >> 4;
    const int s4     = st & 15;
    const int tm     = (s4 >> 2) * 4 + (within >> 2);
    const int tn     = (s4 & 3) * 4 + (within & 3);
    const int t      = t0 + tl;

    __shared__ unsigned short As[3][4096];   // 3 x 8KB
    __shared__ unsigned short Bs[3][4096];

    const int tid  = threadIdx.x;
    const int lane = tid & 63;
    const int wv   = tid >> 6;
    const int wm   = wv >> 1;
    const int wn   = wv & 1;
    const int quad = lane >> 4;
    const int lr   = lane & 15;

    const unsigned short* Ab = Pprev + (size_t)tl * NN * NN;
    const unsigned short* Bb = gnt   + (size_t)tl * NN * NN;

    const int srow = lane >> 2;
    const int sko  = (lane & 3) * 8;

    // per-thread staging source rows (k0 added per iteration)
    const int chunk0 = wv;          // ii=0
    const int chunk1 = 4 + wv;      // ii=1
    const unsigned short* ga0 = Ab + (size_t)(tm * 128 + chunk0 * 16 + srow) * NN + sko;
    const unsigned short* ga1 = Ab + (size_t)(tm * 128 + chunk1 * 16 + srow) * NN + sko;
    const unsigned short* gb0 = Bb + (size_t)(tn * 128 + chunk0 * 16 + srow) * NN + sko;
    const unsigned short* gb1 = Bb + (size_t)(tn * 128 + chunk1 * 16 + srow) * NN + sko;

    f32x4 acc[4][4];
    #pragma unroll
    for (int i = 0; i < 4; ++i)
        #pragma unroll
        for (int j = 0; j < 4; ++j)
            acc[i][j] = (f32x4){0.0f, 0.0f, 0.0f, 0.0f};

    auto stage = [&](int kt, int b) {
        const int k0 = kt * 32;
        __builtin_amdgcn_global_load_lds((as1_const_void*)(ga0 + k0),
                                         (as3_void*)(&As[b][chunk0 * 512]), 16, 0, 0);
        __builtin_amdgcn_global_load_lds((as1_const_void*)(gb0 + k0),
                                         (as3_void*)(&Bs[b][chunk0 * 512]), 16, 0, 0);
        __builtin_amdgcn_global_load_lds((as1_const_void*)(ga1 + k0),
                                         (as3_void*)(&As[b][chunk1 * 512]), 16, 0, 0);
        __builtin_amdgcn_global_load_lds((as1_const_void*)(gb1 + k0),
                                         (as3_void*)(&Bs[b][chunk1 * 512]), 16, 0, 0);
    };

    stage(0, 0);
    stage(1, 1);

    int b = 0;
    for (int kt = 0; kt < NKT; ++kt) {
        // wait until only the most recent stage (4 loads) is outstanding:
        // drains stage(kt), leaves stage(kt+1) in flight. vmcnt(4), lgkm/exp no-wait.
        __asm__ volatile("" ::: "memory");
        __builtin_amdgcn_s_waitcnt(0xF74);
        __builtin_amdgcn_s_barrier();
        __asm__ volatile("" ::: "memory");

        if (kt + 2 < NKT) {
            int bn = b + 2; if (bn >= 3) bn -= 3;
            stage(kt + 2, bn);
        }

        bf16x8 af[4], bfr[4];
        #pragma unroll
        for (int i = 0; i < 4; ++i)
            af[i] = *(const bf16x8*)(&As[b][(wm * 64 + i * 16 + lr) * 32 + quad * 8]);
        #pragma unroll
        for (int j = 0; j < 4; ++j)
            bfr[j] = *(const bf16x8*)(&Bs[b][(wn * 64 + j * 16 + lr) * 32 + quad * 8]);
        #pragma unroll
        for (int i = 0; i < 4; ++i)
            #pragma unroll
            for (int j = 0; j < 4; ++j)
                acc[i][j] = __builtin_amdgcn_mfma_f32_16x16x32_bf16(af[i], bfr[j], acc[i][j], 0, 0, 0);

        ++b; if (b >= 3) b -= 3;
    }

    float wk = w[t * KST + kstep];
    wk = fminf(fmaxf(wk, 0.0f), 1.0f);
    const float om = 1.0f - wk;

    #pragma unroll
    for (int i = 0; i < 4; ++i) {
        #pragma unroll
        for (int v = 0; v < 4; ++v) {
            const int m = tm * 128 + wm * 64 + i * 16 + quad * 4 + v;
            const size_t pbase = (size_t)tl * NN * NN + (size_t)m * NN;
            #pragma unroll
            for (int j = 0; j < 4; ++j) {
                const int n = tn * 128 + wn * 64 + j * 16 + lr;
                float val = wk * acc[i][j][v] + (m == n ? om : 0.0f);
                Pnext[pbase + n] = f2bf_bits(val);
            }
        }
    }
}

// ---- out[m][t][:] = LayerNorm( sum_k P_k[m][:] ), P_k bf16 ----
__global__ __launch_bounds__(256) void ln_kernel(const unsigned short* __restrict__ Pall,
                                                 const float* __restrict__ gamma,
                                                 const float* __restrict__ beta,
                                                 float* __restrict__ out,
                                                 int t0, size_t strideK) {
    const int m  = blockIdx.x;
    const int tl = blockIdx.y;
    const int t  = t0 + tl;
    const int tid = threadIdx.x;
    const int j = tid * 8;

    const size_t rbase = (size_t)tl * NN * NN + (size_t)m * NN + j;
    float v[8] = {0, 0, 0, 0, 0, 0, 0, 0};
    #pragma unroll
    for (int k = 0; k < KST; ++k) {
        u16x8 pv = *(const u16x8*)(Pall + (size_t)k * strideK + rbase);
        #pragma unroll
        for (int e = 0; e < 8; ++e) v[e] += bf2f(pv[e]);
    }

    float s = 0.0f;
    #pragma unroll
    for (int e = 0; e < 8; ++e) s += v[e];
    #pragma unroll
    for (int mm = 32; mm >= 1; mm >>= 1) s += __shfl_xor(s, mm, 64);
    __shared__ float red[4];
    if ((tid & 63) == 0) red[tid >> 6] = s;
    __syncthreads();
    const float mu = (red[0] + red[1] + red[2] + red[3]) * (1.0f / NN);

    float q = 0.0f;
    float dx[8];
    #pragma unroll
    for (int e = 0; e < 8; ++e) { dx[e] = v[e] - mu; q += dx[e] * dx[e]; }
    __syncthreads();
    #pragma unroll
    for (int mm = 32; mm >= 1; mm >>= 1) q += __shfl_xor(q, mm, 64);
    if ((tid & 63) == 0) red[tid >> 6] = q;
    __syncthreads();
    const float var = (red[0] + red[1] + red[2] + red[3]) * (1.0f / NN);
    const float sc = rsqrtf(var + 1e-5f);

    float4 g0 = *(const float4*)(gamma + j);
    float4 g1 = *(const float4*)(gamma + j + 4);
    float4 b0 = *(const float4*)(beta + j);
    float4 b1 = *(const float4*)(beta + j + 4);
    const size_t ob = ((size_t)m * TT + t) * NN + j;
    float4 o0, o1;
    o0.x = dx[0] * sc * g0.x + b0.x;  o0.y = dx[1] * sc * g0.y + b0.y;
    o0.z = dx[2] * sc * g0.z + b0.z;  o0.w = dx[3] * sc * g0.w + b0.w;
    o1.x = dx[4] * sc * g1.x + b1.x;  o1.y = dx[5] * sc * g1.y + b1.y;
    o1.z = dx[6] * sc * g1.z + b1.z;  o1.w = dx[7] * sc * g1.w + b1.w;
    *(float4*)(out + ob)     = o0;
    *(float4*)(out + ob + 4) = o1;
}

extern "C" void kernel_launch(void* const* d_in, const int* in_sizes, int n_in,
                              void* d_out, int out_size, void* d_ws, size_t ws_size,
                              hipStream_t stream) {
    (void)in_sizes; (void)n_in; (void)out_size;
    const float* x     = (const float*)d_in[0];
    const float* w     = (const float*)d_in[1];
    const float* gamma = (const float*)d_in[2];
    const float* beta  = (const float*)d_in[3];
    float* out = (float*)d_out;

    char* ws = (char*)d_ws;
    float* deg = (float*)ws;
    size_t off = ((size_t)TT * NN * sizeof(float) + 255) & ~(size_t)255;
    const size_t per_t = (size_t)NN * NN * sizeof(unsigned short);   // 8 MB
    size_t avail = ws_size > off ? ws_size - off : 0;
    int TB = (int)(avail / ((1 + KST) * per_t));
    if (TB < 1) TB = 1;
    if (TB > TT) TB = TT;
    unsigned short* gnt  = (unsigned short*)(ws + off);
    unsigned short* Pall = gnt + (size_t)TB * NN * NN;
    const size_t strideK = (size_t)TB * NN * NN;

    deg_kernel<<<dim3(NN, TT), 256, 0, stream>>>(x, deg);

    for (int t0 = 0; t0 < TT; t0 += TB) {
        const int tb = (TT - t0) < TB ? (TT - t0) : TB;
        gnt_init_kernel<<<dim3(32, 32, tb), 256, 0, stream>>>(x, deg, w, gnt, Pall, t0);
        for (int k = 2; k <= KST; ++k) {
            const unsigned short* Pp = Pall + (size_t)(k - 2) * strideK;
            unsigned short*       Pn = Pall + (size_t)(k - 1) * strideK;
            gemm_step<<<dim3(256 * tb), 256, 0, stream>>>(Pp, gnt, w, Pn, t0, k - 1);
        }
        ln_kernel<<<dim3(NN, tb), 256, 0, stream>>>(Pall, gamma, beta, out, t0, strideK);
    }
}